// Round 4
// baseline (437.094 us; speedup 1.0000x reference)
//
#include <hip/hip_runtime.h>
#include <hip/hip_cooperative_groups.h>

namespace cg = cooperative_groups;

#define T_FRAMES 256
#define D_IN 80
#define CCH 256
#define CCEP 222
#define FFT_N 1024
#define HOP 256
#define WINL 512
#define PF_KT 128
#define ZLEN 65536

__device__ __forceinline__ unsigned br10(unsigned x) { return __brev(x) >> 22; }

__global__ __launch_bounds__(512) void mega_k(
    const float* __restrict__ x, const float* __restrict__ z,
    const float* __restrict__ w1, const float* __restrict__ b1,
    const float* __restrict__ w2, const float* __restrict__ b2,
    const float* __restrict__ w3, const float* __restrict__ b3,
    const float* __restrict__ pf_w, const float* __restrict__ pf_b,
    const float* __restrict__ quef, const float* __restrict__ win,
    float* __restrict__ out, float* __restrict__ ws) {
  cg::grid_group grid = cg::this_grid();
  __shared__ float smem[3584];  // 14 KB, aliased per stage

  // workspace layout (floats)
  float* w1t  = ws;                 // 240*256
  float* w2t  = w1t + 61440;        // 768*256
  float* w3t  = w2t + 196608;       // 768*222
  float* h1   = w3t + 170496;       // 256*256
  float* h2p  = h1 + 65536;         // 4*256*256
  float* ccp  = h2p + 262144;       // 4*256*222
  float* outw = ccp + 227328;       // 256*512

  const int b = blockIdx.x;
  const int tid = threadIdx.x;
  const int gid = b * 512 + tid;

  // ---- stage 0: weight transpose (Cout, Cin*K) -> (Cin*K, Cout) ----
  for (int idx = gid; idx < 240 * 256; idx += 131072) { int i = idx >> 8, c = idx & 255; w1t[idx] = w1[c * 240 + i]; }
  for (int idx = gid; idx < 768 * 256; idx += 131072) { int i = idx >> 8, c = idx & 255; w2t[idx] = w2[c * 768 + i]; }
  for (int idx = gid; idx < 768 * CCEP; idx += 131072) { int i = idx / CCEP, c = idx - i * CCEP; w3t[idx] = w3[c * 768 + i]; }
  __threadfence();
  grid.sync();

  // ---- stage 1: conv1 (T,80)->(T,256) K=3 relu. blocks 0..63, 4 frames each ----
  {
    float* xs = smem;  // [6][80]
    int t0 = b * 4;
    if (b < 64) {
      for (int i = tid; i < 6 * D_IN; i += 512) {
        int r = i / D_IN, cin = i - r * D_IN;
        int tt = t0 - 1 + r;
        xs[i] = (tt >= 0 && tt < T_FRAMES) ? x[tt * D_IN + cin] : 0.f;
      }
    }
    __syncthreads();
    if (b < 64 && tid < 256) {
      int c = tid;
      float a0 = b1[c], a1 = a0, a2 = a0, a3 = a0;
      int i = 0;
      for (int cin = 0; cin < D_IN; ++cin) {
        #pragma unroll
        for (int k = 0; k < 3; ++k, ++i) {
          float w = w1t[i * 256 + c];
          a0 += xs[(k + 0) * D_IN + cin] * w;
          a1 += xs[(k + 1) * D_IN + cin] * w;
          a2 += xs[(k + 2) * D_IN + cin] * w;
          a3 += xs[(k + 3) * D_IN + cin] * w;
        }
      }
      h1[(t0 + 0) * CCH + c] = fmaxf(a0, 0.f);
      h1[(t0 + 1) * CCH + c] = fmaxf(a1, 0.f);
      h1[(t0 + 2) * CCH + c] = fmaxf(a2, 0.f);
      h1[(t0 + 3) * CCH + c] = fmaxf(a3, 0.f);
    }
  }
  __threadfence();
  grid.sync();

  // ---- stage 2: conv2 split-K x4, partials (no bias/relu) ----
  {
    float* hs = smem;  // [6][64]
    int kc = b & 3, t0 = (b >> 2) * 4, cbase = kc * 64;
    for (int i = tid; i < 6 * 64; i += 512) {
      int r = i >> 6, cin = i & 63;
      int tt = t0 - 1 + r;
      hs[i] = (tt >= 0 && tt < T_FRAMES) ? h1[tt * CCH + cbase + cin] : 0.f;
    }
    __syncthreads();
    if (tid < 256) {
      int c = tid;
      float a0 = 0.f, a1 = 0.f, a2 = 0.f, a3 = 0.f;
      int i = cbase * 3;
      for (int cin = 0; cin < 64; ++cin) {
        #pragma unroll
        for (int k = 0; k < 3; ++k, ++i) {
          float w = w2t[i * 256 + c];
          a0 += hs[(k + 0) * 64 + cin] * w;
          a1 += hs[(k + 1) * 64 + cin] * w;
          a2 += hs[(k + 2) * 64 + cin] * w;
          a3 += hs[(k + 3) * 64 + cin] * w;
        }
      }
      int ob = (kc << 8);
      h2p[(ob + t0 + 0) * CCH + c] = a0;
      h2p[(ob + t0 + 1) * CCH + c] = a1;
      h2p[(ob + t0 + 2) * CCH + c] = a2;
      h2p[(ob + t0 + 3) * CCH + c] = a3;
    }
  }
  __threadfence();
  grid.sync();

  // ---- stage 3: conv3 split-K x4 (sums conv2 partials + bias2 + relu on load) ----
  {
    float* hs = smem;  // [6][64]
    int kc = b & 3, t0 = (b >> 2) * 4, cbase = kc * 64;
    for (int i = tid; i < 6 * 64; i += 512) {
      int r = i >> 6, cin = i & 63;
      int tt = t0 - 1 + r;
      float v = 0.f;
      if (tt >= 0 && tt < T_FRAMES) {
        int idx = tt * CCH + cbase + cin;
        v = b2[cbase + cin] + h2p[idx] + h2p[65536 + idx] + h2p[131072 + idx] + h2p[196608 + idx];
        v = fmaxf(v, 0.f);
      }
      hs[i] = v;
    }
    __syncthreads();
    if (tid < CCEP) {
      int c = tid;
      float a0 = 0.f, a1 = 0.f, a2 = 0.f, a3 = 0.f;
      int i = cbase * 3;
      for (int cin = 0; cin < 64; ++cin) {
        #pragma unroll
        for (int k = 0; k < 3; ++k, ++i) {
          float w = w3t[i * CCEP + c];
          a0 += hs[(k + 0) * 64 + cin] * w;
          a1 += hs[(k + 1) * 64 + cin] * w;
          a2 += hs[(k + 2) * 64 + cin] * w;
          a3 += hs[(k + 3) * 64 + cin] * w;
        }
      }
      int ob = (kc << 8);
      ccp[(ob + t0 + 0) * CCEP + c] = a0;
      ccp[(ob + t0 + 1) * CCEP + c] = a1;
      ccp[(ob + t0 + 2) * CCEP + c] = a2;
      ccp[(ob + t0 + 3) * CCEP + c] = a3;
    }
  }
  __threadfence();
  grid.sync();

  // ---- stage 4: FFT -> 10^(Re/10),phase=Im -> IFFT -> LTV + window. 1 frame/block ----
  {
    float* re = smem;         // [1024]
    float* im = smem + 1024;  // [1024]
    float* ip = smem + 2048;  // [1024]
    float* fr = smem + 3072;  // [512]
    int t = b;
    // bit-reversed zero-padded cepstrum load (pad=401), summing 4 conv3 partials + b3, /quef
    for (int i = tid; i < FFT_N; i += 512) {
      unsigned q = br10((unsigned)i);
      float v = 0.f;
      if (q >= 401u && q < 623u) {
        int cq = (int)(q - 401u);
        int base = t * CCEP + cq;
        v = (b3[cq] + ccp[base] + ccp[256 * CCEP + base] + ccp[512 * CCEP + base] + ccp[768 * CCEP + base]) / quef[cq];
      }
      re[i] = v; im[i] = 0.f;
    }
    {
      int idx = t * HOP + tid - 255;  // frames[t,s] = z[t*HOP + s - 255]
      fr[tid] = (idx >= 0 && idx < ZLEN) ? z[idx] : 0.f;
    }
    __syncthreads();
    // forward DIT radix-2 (bit-reversed in, natural out)
    #pragma unroll
    for (int s = 1; s <= 10; ++s) {
      int half = 1 << (s - 1);
      int pos = tid & (half - 1);
      int i1 = ((tid >> (s - 1)) << s) + pos;
      int i2 = i1 + half;
      float ang = (-6.283185307179586f / (float)(1 << s)) * (float)pos;
      float sn, cs; __sincosf(ang, &sn, &cs);
      float ar = re[i2], ai = im[i2];
      float tr = cs * ar - sn * ai;
      float ti = cs * ai + sn * ar;
      float ur = re[i1], ui = im[i1];
      re[i1] = ur + tr; im[i1] = ui + ti;
      re[i2] = ur - tr; im[i2] = ui - ti;
      __syncthreads();
    }
    // spectral transform
    for (int f = tid; f < FFT_N; f += 512) {
      float mag = __expf(re[f] * 0.23025850929940457f);
      float sn, cs; __sincosf(im[f], &sn, &cs);
      re[f] = mag * cs; im[f] = mag * sn;
    }
    __syncthreads();
    // inverse DIF radix-2 (natural in, bit-reversed out), e^{+i}
    #pragma unroll
    for (int s = 10; s >= 1; --s) {
      int half = 1 << (s - 1);
      int pos = tid & (half - 1);
      int i1 = ((tid >> (s - 1)) << s) + pos;
      int i2 = i1 + half;
      float ang = (6.283185307179586f / (float)(1 << s)) * (float)pos;
      float sn, cs; __sincosf(ang, &sn, &cs);
      float ur = re[i1], ui = im[i1];
      float vr = re[i2], vi = im[i2];
      re[i1] = ur + vr; im[i1] = ui + vi;
      float dr = ur - vr, di = ui - vi;
      re[i2] = cs * dr - sn * di;
      im[i2] = cs * di + sn * dr;
      __syncthreads();
    }
    const float inv = 1.0f / (float)FFT_N;
    for (int i = tid; i < FFT_N; i += 512) ip[br10((unsigned)i)] = re[i] * inv;
    __syncthreads();
    // LTV: out[t,w] = sum_s fr[s]*ip[511-w+s], x4 unrolled with uniform b128 fr reads
    float acc = 0.f;
    int base = 511 - tid;
    const float4* fr4 = (const float4*)fr;
    #pragma unroll 4
    for (int s4 = 0; s4 < WINL / 4; ++s4) {
      float4 f = fr4[s4];
      int p = base + s4 * 4;
      acc += f.x * ip[p] + f.y * ip[p + 1] + f.z * ip[p + 2] + f.w * ip[p + 3];
    }
    outw[t * WINL + tid] = acc * win[tid];
  }
  __threadfence();
  grid.sync();

  // ---- stage 5: overlap-add (circular roll over t) + 128-tap postfilter ----
  {
    float* sb = smem;          // [383]
    float* wpf = smem + 384;   // [128]
    int n0 = b * 256;
    for (int i = tid; i < 256 + PF_KT - 1; i += 512) {
      int m = n0 - 63 + i;
      float v = 0.f;
      if (m >= 0 && m < ZLEN) {
        int t = m >> 8, j = m & 255;
        v = outw[t * WINL + j] + outw[((t - 1) & 255) * WINL + HOP + j];
      }
      sb[i] = v;
    }
    if (tid < PF_KT) wpf[tid] = pf_w[tid];
    __syncthreads();
    if (tid < 256) {
      float acc = pf_b[0];
      #pragma unroll 8
      for (int j = 0; j < PF_KT; ++j) acc += sb[tid + j] * wpf[j];
      out[n0 + tid] = acc;
    }
  }
}

extern "C" void kernel_launch(void* const* d_in, const int* in_sizes, int n_in,
                              void* d_out, int out_size, void* d_ws, size_t ws_size,
                              hipStream_t stream) {
  const float* x    = (const float*)d_in[0];
  const float* z    = (const float*)d_in[1];
  const float* w1   = (const float*)d_in[2];
  const float* b1   = (const float*)d_in[3];
  const float* w2   = (const float*)d_in[4];
  const float* b2   = (const float*)d_in[5];
  const float* w3   = (const float*)d_in[6];
  const float* b3   = (const float*)d_in[7];
  const float* pf_w = (const float*)d_in[8];
  const float* pf_b = (const float*)d_in[9];
  const float* quef = (const float*)d_in[10];
  const float* win  = (const float*)d_in[11];
  float* out = (float*)d_out;
  float* ws  = (float*)d_ws;

  void* args[] = { (void*)&x, (void*)&z, (void*)&w1, (void*)&b1, (void*)&w2, (void*)&b2,
                   (void*)&w3, (void*)&b3, (void*)&pf_w, (void*)&pf_b, (void*)&quef,
                   (void*)&win, (void*)&out, (void*)&ws };
  hipLaunchCooperativeKernel((void*)mega_k, dim3(256), dim3(512), args, 0, stream);
}

// Round 5
// 46.240 us; speedup vs baseline: 9.4528x; 9.4528x over previous
//
#include <hip/hip_runtime.h>

#define T_FRAMES 256
#define D_IN 80
#define CCH 256
#define CCEP 222
#define FFT_N 1024
#define HOP 256
#define WINL 512
#define PF_KT 128
#define ZLEN 65536

__device__ __forceinline__ unsigned br10(unsigned x) { return __brev(x) >> 22; }

// ---- K1: conv1 on blocks 0..63 (direct w1 row reads) + w2/w3 transpose on blocks 64..255 ----
__global__ __launch_bounds__(512) void conv1_tr_k(const float* __restrict__ x, const float* __restrict__ w1,
                                                  const float* __restrict__ b1,
                                                  const float* __restrict__ w2, const float* __restrict__ w3,
                                                  float* __restrict__ h1,
                                                  float* __restrict__ w2t, float* __restrict__ w3t) {
  __shared__ float xs[6 * D_IN];
  int b = blockIdx.x, tid = threadIdx.x;
  if (b < 64) {
    int t0 = b * 4;
    for (int i = tid; i < 6 * D_IN; i += 512) {
      int r = i / D_IN, cin = i - r * D_IN;
      int tt = t0 - 1 + r;
      xs[i] = (tt >= 0 && tt < T_FRAMES) ? x[tt * D_IN + cin] : 0.f;
    }
    __syncthreads();
    if (tid < 256) {
      int c = tid;
      const float4* row4 = (const float4*)(w1 + c * 240);  // 240 floats, 16B-aligned
      float a0 = b1[c], a1 = a0, a2 = a0, a3 = a0;
      #define ACC1(wv, cin, kk) { float _w = (wv); \
        a0 += xs[((kk) + 0) * D_IN + (cin)] * _w; \
        a1 += xs[((kk) + 1) * D_IN + (cin)] * _w; \
        a2 += xs[((kk) + 2) * D_IN + (cin)] * _w; \
        a3 += xs[((kk) + 3) * D_IN + (cin)] * _w; }
      #pragma unroll 5
      for (int g = 0; g < 20; ++g) {
        int c0 = g * 4;
        float4 wa = row4[g * 3 + 0];
        float4 wb = row4[g * 3 + 1];
        float4 wc = row4[g * 3 + 2];
        ACC1(wa.x, c0 + 0, 0) ACC1(wa.y, c0 + 0, 1) ACC1(wa.z, c0 + 0, 2) ACC1(wa.w, c0 + 1, 0)
        ACC1(wb.x, c0 + 1, 1) ACC1(wb.y, c0 + 1, 2) ACC1(wb.z, c0 + 2, 0) ACC1(wb.w, c0 + 2, 1)
        ACC1(wc.x, c0 + 2, 2) ACC1(wc.y, c0 + 3, 0) ACC1(wc.z, c0 + 3, 1) ACC1(wc.w, c0 + 3, 2)
      }
      #undef ACC1
      h1[(t0 + 0) * CCH + c] = fmaxf(a0, 0.f);
      h1[(t0 + 1) * CCH + c] = fmaxf(a1, 0.f);
      h1[(t0 + 2) * CCH + c] = fmaxf(a2, 0.f);
      h1[(t0 + 3) * CCH + c] = fmaxf(a3, 0.f);
    }
  } else {
    int g = (b - 64) * 512 + tid;
    const int GS = 192 * 512;
    for (int idx = g; idx < 768 * 256; idx += GS) { int i = idx >> 8, c = idx & 255; w2t[idx] = w2[c * 768 + i]; }
    for (int idx = g; idx < 768 * CCEP; idx += GS) { int i = idx / CCEP, c = idx - i * CCEP; w3t[idx] = w3[c * 768 + i]; }
  }
}

// ---- conv2 split-K: grid (4 kchunks, 64 tgroups). Partials, no bias/relu ----
__global__ __launch_bounds__(256) void conv2_k(const float* __restrict__ h1, const float* __restrict__ w2t,
                                               float* __restrict__ h2part) {
  __shared__ float hs[6][64];
  int kc = blockIdx.x;
  int t0 = blockIdx.y * 4;
  int c = threadIdx.x;
  int cbase = kc * 64;
  for (int i = c; i < 6 * 64; i += 256) {
    int r = i >> 6, cin = i & 63;
    int tt = t0 - 1 + r;
    hs[r][cin] = (tt >= 0 && tt < T_FRAMES) ? h1[tt * CCH + cbase + cin] : 0.f;
  }
  __syncthreads();
  float a0 = 0.f, a1 = 0.f, a2 = 0.f, a3 = 0.f;
  int i = cbase * 3;
  for (int cin = 0; cin < 64; ++cin) {
    #pragma unroll
    for (int k = 0; k < 3; ++k, ++i) {
      float w = w2t[i * 256 + c];
      a0 += hs[k + 0][cin] * w;
      a1 += hs[k + 1][cin] * w;
      a2 += hs[k + 2][cin] * w;
      a3 += hs[k + 3][cin] * w;
    }
  }
  int ob = (kc << 8);
  h2part[(ob + t0 + 0) * CCH + c] = a0;
  h2part[(ob + t0 + 1) * CCH + c] = a1;
  h2part[(ob + t0 + 2) * CCH + c] = a2;
  h2part[(ob + t0 + 3) * CCH + c] = a3;
}

// ---- conv3 split-K: sums h2 partials + bias2 + relu on load; writes ccep partials ----
__global__ __launch_bounds__(256) void conv3_k(const float* __restrict__ h2part, const float* __restrict__ w3t,
                                               const float* __restrict__ b2, float* __restrict__ ccep_part) {
  __shared__ float hs[6][64];
  int kc = blockIdx.x;
  int t0 = blockIdx.y * 4;
  int c = threadIdx.x;
  int cbase = kc * 64;
  for (int i = c; i < 6 * 64; i += 256) {
    int r = i >> 6, cin = i & 63;
    int tt = t0 - 1 + r;
    float v = 0.f;
    if (tt >= 0 && tt < T_FRAMES) {
      int idx = tt * CCH + cbase + cin;
      v = b2[cbase + cin] + h2part[idx] + h2part[65536 + idx] + h2part[131072 + idx] + h2part[196608 + idx];
      v = fmaxf(v, 0.f);
    }
    hs[r][cin] = v;
  }
  __syncthreads();
  if (c < CCEP) {
    float a0 = 0.f, a1 = 0.f, a2 = 0.f, a3 = 0.f;
    int i = cbase * 3;
    for (int cin = 0; cin < 64; ++cin) {
      #pragma unroll
      for (int k = 0; k < 3; ++k, ++i) {
        float w = w3t[i * CCEP + c];
        a0 += hs[k + 0][cin] * w;
        a1 += hs[k + 1][cin] * w;
        a2 += hs[k + 2][cin] * w;
        a3 += hs[k + 3][cin] * w;
      }
    }
    int ob = (kc << 8);
    ccep_part[(ob + t0 + 0) * CCEP + c] = a0;
    ccep_part[(ob + t0 + 1) * CCEP + c] = a1;
    ccep_part[(ob + t0 + 2) * CCEP + c] = a2;
    ccep_part[(ob + t0 + 3) * CCEP + c] = a3;
  }
}

// ---- fused spectral kernel via correlation theorem: ONE fwd FFT (cc + i*fr), Hermitian split,
//      P = conj(F_fr) * SP, ONE inverse FFT -> out[t,w] = c[511-w] * win[w] ----
__global__ __launch_bounds__(512) void fftltv_k(const float* __restrict__ ccp, const float* __restrict__ b3,
                                                const float* __restrict__ quef, const float* __restrict__ z,
                                                const float* __restrict__ win, float* __restrict__ outw) {
  __shared__ float2 U[FFT_N];  // interleaved complex, 8 KB
  int t = blockIdx.x, tid = threadIdx.x;
  // load u[i] = cc_pad[br(i)] + i * fr[br(i)]  (bit-reversed order for DIT)
  for (int i = tid; i < FFT_N; i += 512) {
    unsigned q = br10((unsigned)i);
    float a = 0.f, bv = 0.f;
    if (q >= 401u && q < 623u) {
      int cq = (int)(q - 401u);
      int base = t * CCEP + cq;
      a = (b3[cq] + ccp[base] + ccp[256 * CCEP + base] + ccp[512 * CCEP + base] + ccp[768 * CCEP + base]) / quef[cq];
    }
    if (q < 512u) {
      int idx = t * HOP + (int)q - 255;  // frames[t,s] = z[t*HOP + s - 255]
      bv = (idx >= 0 && idx < ZLEN) ? z[idx] : 0.f;
    }
    U[i] = make_float2(a, bv);
  }
  __syncthreads();
  // forward DIT radix-2 (bit-reversed in, natural out), e^{-i}
  #pragma unroll
  for (int s = 1; s <= 10; ++s) {
    int half = 1 << (s - 1);
    int pos = tid & (half - 1);
    int i1 = ((tid >> (s - 1)) << s) + pos;
    int i2 = i1 + half;
    float ang = (-6.283185307179586f / (float)(1 << s)) * (float)pos;
    float sn, cs; __sincosf(ang, &sn, &cs);
    float2 v2 = U[i2], v1 = U[i1];
    float tr = cs * v2.x - sn * v2.y;
    float ti = cs * v2.y + sn * v2.x;
    U[i1] = make_float2(v1.x + tr, v1.y + ti);
    U[i2] = make_float2(v1.x - tr, v1.y - ti);
    __syncthreads();
  }
  // pointwise: thread j owns bins (j, 1024-j); thread 0 owns (0) and (512).
  {
    int j = tid;
    int mj = (FFT_N - j) & (FFT_N - 1);
    float2 Uj = U[j], Um = U[mj];
    float2 U5j = make_float2(0.f, 0.f);
    if (tid == 0) U5j = U[512];
    // P(Uj,Um): A=(Uj+conj Um)/2 ; B=(Uj-conj Um)/(2i) ; SP=e^{K Re A} e^{i Im A} ; P=conj(B)*SP
    auto pcalc = [](float2 Uj, float2 Um) -> float2 {
      float Ar = 0.5f * (Uj.x + Um.x);
      float Ai = 0.5f * (Uj.y - Um.y);
      float Bx = 0.5f * (Uj.y + Um.y);
      float By = 0.5f * (Um.x - Uj.x);
      float mag = __expf(0.23025850929940457f * Ar);
      float sn, cs; __sincosf(Ai, &sn, &cs);
      float SPx = mag * cs, SPy = mag * sn;
      return make_float2(Bx * SPx + By * SPy, Bx * SPy - By * SPx);
    };
    float2 Pj = pcalc(Uj, Um);
    float2 P5 = (tid == 0) ? pcalc(U5j, U5j) : make_float2(0.f, 0.f);
    __syncthreads();
    U[j] = Pj;
    if (tid == 0) U[512] = P5;
    else U[mj] = make_float2(Pj.x, -Pj.y);  // Hermitian
  }
  __syncthreads();
  // inverse DIF radix-2 (natural in, bit-reversed out), e^{+i}
  #pragma unroll
  for (int s = 10; s >= 1; --s) {
    int half = 1 << (s - 1);
    int pos = tid & (half - 1);
    int i1 = ((tid >> (s - 1)) << s) + pos;
    int i2 = i1 + half;
    float ang = (6.283185307179586f / (float)(1 << s)) * (float)pos;
    float sn, cs; __sincosf(ang, &sn, &cs);
    float2 v1 = U[i1], v2 = U[i2];
    U[i1] = make_float2(v1.x + v2.x, v1.y + v2.y);
    float dr = v1.x - v2.x, di = v1.y - v2.y;
    U[i2] = make_float2(cs * dr - sn * di, cs * di + sn * dr);
    __syncthreads();
  }
  // c[m] at LDS index i where m=br10(i); out[t,w] = c[511-w]*win[w]/N
  const float inv = 1.0f / (float)FFT_N;
  for (int i = tid; i < FFT_N; i += 512) {
    unsigned m = br10((unsigned)i);
    if (m < 512u) {
      int w = 511 - (int)m;
      outw[t * WINL + w] = U[i].x * inv * win[w];
    }
  }
}

// ---- overlap-add (circular roll over t) + 128-tap postfilter ----
__global__ __launch_bounds__(256) void pf_k(const float* __restrict__ outw, const float* __restrict__ pf_w,
                                            const float* __restrict__ pf_b, float* __restrict__ y) {
  __shared__ float sb[256 + PF_KT - 1];
  __shared__ float wpf[PF_KT];
  int n0 = blockIdx.x * 256;
  for (int i = threadIdx.x; i < 256 + PF_KT - 1; i += 256) {
    int m = n0 - 63 + i;
    float v = 0.f;
    if (m >= 0 && m < ZLEN) {
      int t = m >> 8, j = m & 255;
      v = outw[t * WINL + j] + outw[((t - 1) & 255) * WINL + HOP + j];
    }
    sb[i] = v;
  }
  if (threadIdx.x < PF_KT) wpf[threadIdx.x] = pf_w[threadIdx.x];
  __syncthreads();
  float acc = pf_b[0];
  #pragma unroll 8
  for (int j = 0; j < PF_KT; ++j) acc += sb[threadIdx.x + j] * wpf[j];
  y[n0 + threadIdx.x] = acc;
}

extern "C" void kernel_launch(void* const* d_in, const int* in_sizes, int n_in,
                              void* d_out, int out_size, void* d_ws, size_t ws_size,
                              hipStream_t stream) {
  const float* x    = (const float*)d_in[0];
  const float* z    = (const float*)d_in[1];
  const float* w1   = (const float*)d_in[2];
  const float* b1   = (const float*)d_in[3];
  const float* w2   = (const float*)d_in[4];
  const float* b2   = (const float*)d_in[5];
  const float* w3   = (const float*)d_in[6];
  const float* b3   = (const float*)d_in[7];
  const float* pf_w = (const float*)d_in[8];
  const float* pf_b = (const float*)d_in[9];
  const float* quef = (const float*)d_in[10];
  const float* win  = (const float*)d_in[11];
  float* out = (float*)d_out;
  float* ws  = (float*)d_ws;

  // workspace layout (floats)
  float* w2t  = ws;                 // 768*256   = 196608
  float* w3t  = w2t + 196608;       // 768*222   = 170496
  float* h1   = w3t + 170496;       // 256*256   = 65536
  float* h2p  = h1 + 65536;         // 4*256*256 = 262144
  float* ccp  = h2p + 262144;       // 4*256*222 = 227328
  float* outw = ccp + 227328;       // 256*512   = 131072

  conv1_tr_k<<<256, 512, 0, stream>>>(x, w1, b1, w2, w3, h1, w2t, w3t);
  conv2_k<<<dim3(4, 64), 256, 0, stream>>>(h1, w2t, h2p);
  conv3_k<<<dim3(4, 64), 256, 0, stream>>>(h2p, w3t, b2, ccp);
  fftltv_k<<<T_FRAMES, 512, 0, stream>>>(ccp, b3, quef, z, win, outw);
  pf_k<<<ZLEN / 256, 256, 0, stream>>>(outw, pf_w, pf_b, out);
}